// Round 5
// baseline (1824.901 us; speedup 1.0000x reference)
//
#include <hip/hip_runtime.h>
#include <hip/hip_bf16.h>

#define T_STEPS 2048
#define BATCH   64
#define DIN     256
#define DH      256
#define ST      (BATCH * DH)   // 16384 floats per timestep slab

// Raw workgroup barrier WITHOUT the __syncthreads vmcnt(0) drain: LDS ordering
// only (lgkmcnt). Global loads/stores stay in flight across steps; the
// compiler inserts counted vmcnt waits at first use of the loaded regs.
__device__ __forceinline__ void wg_barrier() {
  asm volatile("s_waitcnt lgkmcnt(0)" ::: "memory");
  __builtin_amdgcn_s_barrier();
  asm volatile("" ::: "memory");
}

// ---------------- Phase 1: xproj = x @ W_ih^T + (b_ih + b_hh) ----------------
#define P1_BM 128
#define P1_BN 128
#define P1_KC 32
#define P1_PAD 4

__global__ __launch_bounds__(256) void xproj_kernel(
    const float* __restrict__ x, const float* __restrict__ W,
    const float* __restrict__ b_ih, const float* __restrict__ b_hh,
    float* __restrict__ out) {
  __shared__ float As[P1_KC][P1_BM + P1_PAD];  // [k][m]
  __shared__ float Wt[P1_KC][P1_BN + P1_PAD];  // [k][j]
  const int tid = threadIdx.x;
  const int m0 = blockIdx.x * P1_BM;
  const int j0 = blockIdx.y * P1_BN;
  const int r0 = (tid >> 4) * 8;
  const int c0 = (tid & 15) * 8;
  float acc[8][8] = {};

  for (int kc = 0; kc < DIN; kc += P1_KC) {
    __syncthreads();
#pragma unroll
    for (int s = 0; s < 4; ++s) {
      int idx = s * 256 + tid;
      int row = idx >> 3;
      int c4  = (idx & 7) << 2;
      float4 v = *reinterpret_cast<const float4*>(
          &x[(size_t)(m0 + row) * DIN + kc + c4]);
      As[c4 + 0][row] = v.x; As[c4 + 1][row] = v.y;
      As[c4 + 2][row] = v.z; As[c4 + 3][row] = v.w;
    }
#pragma unroll
    for (int s = 0; s < 4; ++s) {
      int idx = s * 256 + tid;
      int row = idx >> 3;
      int c4  = (idx & 7) << 2;
      float4 v = *reinterpret_cast<const float4*>(
          &W[(size_t)(j0 + row) * DIN + kc + c4]);
      Wt[c4 + 0][row] = v.x; Wt[c4 + 1][row] = v.y;
      Wt[c4 + 2][row] = v.z; Wt[c4 + 3][row] = v.w;
    }
    __syncthreads();
#pragma unroll
    for (int k = 0; k < P1_KC; ++k) {
      float4 a0 = *reinterpret_cast<const float4*>(&As[k][r0]);
      float4 a1 = *reinterpret_cast<const float4*>(&As[k][r0 + 4]);
      float4 w0 = *reinterpret_cast<const float4*>(&Wt[k][c0]);
      float4 w1 = *reinterpret_cast<const float4*>(&Wt[k][c0 + 4]);
      float a[8] = {a0.x, a0.y, a0.z, a0.w, a1.x, a1.y, a1.z, a1.w};
      float wv[8] = {w0.x, w0.y, w0.z, w0.w, w1.x, w1.y, w1.z, w1.w};
#pragma unroll
      for (int i = 0; i < 8; ++i)
#pragma unroll
        for (int jj = 0; jj < 8; ++jj)
          acc[i][jj] = fmaf(a[i], wv[jj], acc[i][jj]);
    }
  }

  float bias[8];
#pragma unroll
  for (int jj = 0; jj < 8; ++jj) bias[jj] = b_ih[j0 + c0 + jj] + b_hh[j0 + c0 + jj];
#pragma unroll
  for (int i = 0; i < 8; ++i) {
    size_t m = (size_t)(m0 + r0 + i);
#pragma unroll
    for (int j4 = 0; j4 < 2; ++j4) {
      float4 v;
      v.x = acc[i][j4 * 4 + 0] + bias[j4 * 4 + 0];
      v.y = acc[i][j4 * 4 + 1] + bias[j4 * 4 + 1];
      v.z = acc[i][j4 * 4 + 2] + bias[j4 * 4 + 2];
      v.w = acc[i][j4 * 4 + 3] + bias[j4 * 4 + 3];
      *reinterpret_cast<float4*>(&out[m * DH + j0 + c0 + j4 * 4]) = v;
    }
  }
}

// ---------------- Phase 2: sequential scan, one WG per batch element --------
// Weights register-resident (launch_bounds(512,1): 2 waves/SIMD, ~220 VGPR).
// 8-step supersteps: xp loaded 2 supersteps ahead (ping-pong reg sets), h
// stored 1 superstep behind; raw s_barrier per step (no vmcnt drain).

#define RNN_STEP(i, XP, H)                                                     \
  {                                                                            \
    const float4 hc0 = *reinterpret_cast<const float4*>(&hbuf[(i) & 1][0][kg][0]); \
    const float4 hc1 = *reinterpret_cast<const float4*>(&hbuf[(i) & 1][1][kg][0]); \
    const float4 hc2 = *reinterpret_cast<const float4*>(&hbuf[(i) & 1][2][kg][0]); \
    const float4 hc3 = *reinterpret_cast<const float4*>(&hbuf[(i) & 1][3][kg][0]); \
    float p[8];                                                                \
    _Pragma("unroll")                                                          \
    for (int r = 0; r < 8; ++r) {                                              \
      float a = 0.f;                                                           \
      a = fmaf(w[r][0].x, hc0.x, a); a = fmaf(w[r][0].y, hc0.y, a);            \
      a = fmaf(w[r][0].z, hc0.z, a); a = fmaf(w[r][0].w, hc0.w, a);            \
      a = fmaf(w[r][1].x, hc1.x, a); a = fmaf(w[r][1].y, hc1.y, a);            \
      a = fmaf(w[r][1].z, hc1.z, a); a = fmaf(w[r][1].w, hc1.w, a);            \
      a = fmaf(w[r][2].x, hc2.x, a); a = fmaf(w[r][2].y, hc2.y, a);            \
      a = fmaf(w[r][2].z, hc2.z, a); a = fmaf(w[r][2].w, hc2.w, a);            \
      a = fmaf(w[r][3].x, hc3.x, a); a = fmaf(w[r][3].y, hc3.y, a);            \
      a = fmaf(w[r][3].z, hc3.z, a); a = fmaf(w[r][3].w, hc3.w, a);            \
      p[r] = a;                                                                \
    }                                                                          \
    float q[4];                                                                \
    _Pragma("unroll")                                                          \
    for (int ii = 0; ii < 4; ++ii) {                                           \
      float sent = b0 ? p[ii] : p[4 + ii];                                     \
      float recv = __shfl_xor(sent, 1);                                        \
      q[ii] = (b0 ? p[4 + ii] : p[ii]) + recv;                                 \
    }                                                                          \
    float u[2];                                                                \
    _Pragma("unroll")                                                          \
    for (int ii = 0; ii < 2; ++ii) {                                           \
      float sent = b1 ? u##_dummy_q(q, ii) : q[2 + ii];                        \
      float recv = __shfl_xor(sent, 2);                                        \
      u[ii] = (b1 ? q[2 + ii] : q[ii]) + recv;                                 \
    }                                                                          \
    float sent = b2 ? u[0] : u[1];                                             \
    float v = (b2 ? u[1] : u[0]) + __shfl_xor(sent, 4);                        \
    v += __shfl_xor(v, 8);                                                     \
    const float s = v + XP[i];                                                 \
    const float e = __expf(2.0f * s);                                          \
    const float h = 1.0f - 2.0f * __builtin_amdgcn_rcpf(e + 1.0f);             \
    H[i] = h;                                                                  \
    if (writer) hbuf[((i) & 1) ^ 1][wslot][jred >> 4][jred & 3] = h;           \
    wg_barrier();                                                              \
  }

// (helper to keep the macro text identical to the verified R4 butterfly)
#define u_dummy_q(q, ii) q[ii]

#define RNN_SUPER(XP, H)                                                       \
  RNN_STEP(0, XP, H) RNN_STEP(1, XP, H) RNN_STEP(2, XP, H) RNN_STEP(3, XP, H)  \
  RNN_STEP(4, XP, H) RNN_STEP(5, XP, H) RNN_STEP(6, XP, H) RNN_STEP(7, XP, H)

#define RNN_STORE8(K, H)                                                       \
  {                                                                            \
    if (writer) {                                                              \
      _Pragma("unroll")                                                        \
      for (int i = 0; i < 8; ++i)                                              \
        outbuf[(size_t)((K) * 8 + i) * ST + base + jred] = H[i];               \
    }                                                                          \
  }

#define RNN_LOAD8(K, XP)                                                       \
  {                                                                            \
    _Pragma("unroll")                                                          \
    for (int i = 0; i < 8; ++i)                                                \
      XP[i] = outbuf[(size_t)((K) * 8 + i) * ST + base + jred];                \
  }

__global__ __launch_bounds__(512, 1) void rnn_scan_kernel(
    const float* __restrict__ hx, const float* __restrict__ W_hh,
    float* __restrict__ outbuf,            // [T*B*DH], xproj in / h out (in place)
    float* __restrict__ hlast) {           // [B*DH]
  const int b    = blockIdx.x;
  const int tid  = threadIdx.x;
  const int wave = tid >> 6;
  const int lane = tid & 63;
  const int kg   = lane & 15;              // k-group: h[kg*16 .. kg*16+15]
  const int jg   = wave * 4 + (lane >> 4); // j-group: j = jg*8 + r
  const int jred = jg * 8 + ((lane & 1) << 2) + (lane & 2) + ((lane >> 2) & 1);
  const bool b0 = lane & 1, b1 = lane & 2, b2 = lane & 4;
  const bool writer = !(lane & 8);
  const int  wslot  = (jred >> 2) & 3;

  // weights register-resident: w[r][c] = W_hh[jg*8+r][kg*16 + 4c .. +3]
  float4 w[8][4];
#pragma unroll
  for (int r = 0; r < 8; ++r)
#pragma unroll
    for (int c = 0; c < 4; ++c)
      w[r][c] = *reinterpret_cast<const float4*>(
          &W_hh[(size_t)(jg * 8 + r) * DH + kg * 16 + c * 4]);

  // h double-buffer: hbuf[buf][chunk][kg][e]; h[kg*16+4c+e] -> hbuf[.][c][kg][e]
  __shared__ float hbuf[2][4][16][4];
  if (tid < DH) hbuf[0][(tid >> 2) & 3][tid >> 4][tid & 3] = hx[(size_t)b * DH + tid];

  const size_t base = (size_t)b * DH;

  float xpa[8], xpb[8], ha[8], hb[8];
  RNN_LOAD8(0, xpa)                        // steps 0..7
  RNN_LOAD8(1, xpb)                        // steps 8..15
  __syncthreads();                         // one-time full drain + hx visible

#pragma unroll 1
  for (int kk = 0; kk < 128; ++kk) {
    // ---- superstep 2kk: consume xpa, produce ha ----
    if (kk > 0) { RNN_STORE8(2 * kk - 1, hb) }   // steps of superstep 2kk-1
    RNN_SUPER(xpa, ha)
    if (kk < 127) { RNN_LOAD8(2 * kk + 2, xpa) } // for superstep 2kk+2
    // ---- superstep 2kk+1: consume xpb, produce hb ----
    RNN_STORE8(2 * kk, ha)
    RNN_SUPER(xpb, hb)
    if (kk < 127) { RNN_LOAD8(2 * kk + 3, xpb) } // for superstep 2kk+3
  }
  RNN_STORE8(255, hb)                      // steps 2040..2047
  if (writer) hlast[base + jred] = hb[7];  // h at t = 2047

  (void)wave;
}

extern "C" void kernel_launch(void* const* d_in, const int* in_sizes, int n_in,
                              void* d_out, int out_size, void* d_ws, size_t ws_size,
                              hipStream_t stream) {
  const float* x    = (const float*)d_in[0];
  const float* hx   = (const float*)d_in[1];
  const float* W_ih = (const float*)d_in[2];
  const float* W_hh = (const float*)d_in[3];
  const float* b_ih = (const float*)d_in[4];
  const float* b_hh = (const float*)d_in[5];
  float* out   = (float*)d_out;
  float* hlast = out + (size_t)T_STEPS * BATCH * DH;

  dim3 g1((T_STEPS * BATCH) / P1_BM, DH / P1_BN);
  xproj_kernel<<<g1, 256, 0, stream>>>(x, W_ih, b_ih, b_hh, out);

  rnn_scan_kernel<<<BATCH, 512, 0, stream>>>(hx, W_hh, out, hlast);
}